// Round 3
// baseline (1531.832 us; speedup 1.0000x reference)
//
#include <hip/hip_runtime.h>
#include <stdint.h>

#define HIDDEN 512
#define EMBED  256
#define VTGT   50257
#define VTGT_PAD 50304
#define TLEN   512
#define GATE3  1536
#define RKB    128   // recurrence blocks, 1 wave (64 threads) each

typedef float f32x4 __attribute__((ext_vector_type(4)));
typedef unsigned int u32;
typedef unsigned int u32x4 __attribute__((ext_vector_type(4)));

__device__ __forceinline__ unsigned short f2bf(float f) {
  union { float f; unsigned u; } v; v.f = f;
  unsigned u = v.u;
  unsigned r = (u + 0x7FFFu + ((u >> 16) & 1u)) >> 16;
  return (unsigned short)r;
}

__device__ __forceinline__ float sigm(float x) {
  return 1.f / (1.f + __expf(-x));
}

// ---------- encoder: gi = Wih_e @ x_last + bih_e ----------
__global__ void kenc1(const int* source, const float* emb_e, const float* Wih_e,
                      const float* bih_e, float* genc) {
  __shared__ float xs[EMBED];
  int tid = threadIdx.x;
  int tok = source[511];
  if (tid < EMBED) xs[tid] = emb_e[(size_t)tok * EMBED + tid];
  __syncthreads();
  int j = blockIdx.x * 256 + tid;
  const float* w = Wih_e + (size_t)j * EMBED;
  float acc = bih_e[j];
  for (int k = 0; k < EMBED; k += 4) {
    float4 wv = *(const float4*)(w + k);
    acc += wv.x * xs[k] + wv.y * xs[k + 1] + wv.z * xs[k + 2] + wv.w * xs[k + 3];
  }
  genc[j] = acc;
}

// ---------- encoder gates: publish h^0 with tag 0 stuffed in low 9 mantissa bits ----------
__global__ void kenc2(const float* genc, const float* bhh_e, u32* hpub) {
  int e = threadIdx.x; // 512 threads
  float r = sigm(genc[e] + bhh_e[e]);
  float z = sigm(genc[e + 512] + bhh_e[e + 512]);
  float n = tanhf(genc[e + 1024] + r * bhh_e[e + 1024]);
  float h = (1.f - z) * n;
  hpub[e] = __float_as_uint(h) & ~511u;  // buffer 0, tag = 0
  hpub[HIDDEN + e] = 0u;                 // buffer 1: tag 0 (even) never matches an odd want
}

// ---------- GI[t][j] = Wih_d @ relu(emb_d[tok_t]) + bih_d ----------
__global__ __launch_bounds__(256) void kgi(const int* target, const float* emb_d,
                                           const float* Wih_d, const float* bih_d,
                                           float* GI) {
  __shared__ float Xs[32][EMBED];
  int tid = threadIdx.x;
  int j0 = blockIdx.x * 128;
  int t0 = blockIdx.y * 32;
  for (int idx = tid; idx < 32 * EMBED; idx += 256) {
    int tt = idx >> 8, c = idx & 255;
    int t = t0 + tt;
    int tok = (t == 0) ? 0 : target[t - 1];
    float v = emb_d[(size_t)tok * EMBED + c];
    Xs[tt][c] = v > 0.f ? v : 0.f;
  }
  __syncthreads();
  int jl = tid & 127, tg = tid >> 7;
  int j = j0 + jl;
  const float* w = Wih_d + (size_t)j * EMBED;
  float acc[16];
#pragma unroll
  for (int i = 0; i < 16; ++i) acc[i] = 0.f;
  for (int k = 0; k < EMBED; k += 4) {
    float4 wv = *(const float4*)(w + k);
#pragma unroll
    for (int i = 0; i < 16; ++i) {
      int tl = tg * 16 + i;
      acc[i] += wv.x * Xs[tl][k] + wv.y * Xs[tl][k + 1] +
                wv.z * Xs[tl][k + 2] + wv.w * Xs[tl][k + 3];
    }
  }
  float b = bih_d[j];
#pragma unroll
  for (int i = 0; i < 16; ++i) {
    int t = t0 + tg * 16 + i;
    GI[(size_t)t * GATE3 + j] = acc[i] + b;
  }
}

// ---------- Wout f32 -> bf16 (padded rows zeroed) ----------
__global__ void kwout(const float* Wout, unsigned short* WB) {
  size_t npairs = (size_t)VTGT_PAD * HIDDEN / 2;
  size_t stride = (size_t)gridDim.x * blockDim.x;
  for (size_t p = (size_t)blockIdx.x * blockDim.x + threadIdx.x; p < npairs; p += stride) {
    size_t i = p * 2;
    int j = (int)(i / HIDDEN);
    float a = 0.f, b = 0.f;
    if (j < VTGT) { float2 v = *(const float2*)(Wout + i); a = v.x; b = v.y; }
    *(unsigned*)(WB + i) = (unsigned)f2bf(a) | ((unsigned)f2bf(b) << 16);
  }
}

// 8 coherent 16B loads, all in flight, one wait. (val|tag) atomic per dword.
__device__ __forceinline__ void poll8(const u32* base, u32x4 c[8]) {
  asm volatile(
    "global_load_dwordx4 %[c0], %[a], off sc0 sc1\n\t"
    "global_load_dwordx4 %[c1], %[a], off offset:16 sc0 sc1\n\t"
    "global_load_dwordx4 %[c2], %[a], off offset:32 sc0 sc1\n\t"
    "global_load_dwordx4 %[c3], %[a], off offset:48 sc0 sc1\n\t"
    "global_load_dwordx4 %[c4], %[a], off offset:64 sc0 sc1\n\t"
    "global_load_dwordx4 %[c5], %[a], off offset:80 sc0 sc1\n\t"
    "global_load_dwordx4 %[c6], %[a], off offset:96 sc0 sc1\n\t"
    "global_load_dwordx4 %[c7], %[a], off offset:112 sc0 sc1\n\t"
    "s_waitcnt vmcnt(0)"
    : [c0]"=v"(c[0]), [c1]"=v"(c[1]), [c2]"=v"(c[2]), [c3]"=v"(c[3]),
      [c4]"=v"(c[4]), [c5]"=v"(c[5]), [c6]"=v"(c[6]), [c7]"=v"(c[7])
    : [a]"v"(base)
    : "memory");
}

// ---------- sequential GRU recurrence: barrier-free, LDS-free, tag-in-mantissa ----------
__global__ __launch_bounds__(64) void krec(const float* Whh, const float* bhh,
                                           const float* GI, u32* hpub,
                                           unsigned short* HB) {
  int tid = threadIdx.x;       // 0..63
  int p = tid & 15;            // k-slice owner
  int eg = tid >> 4;           // 0..3
  int e = blockIdx.x * 4 + eg;
  int k0 = p * 32;
  // persistent weights in VGPRs: rows e, e+512, e+1024, cols k0..k0+31
  float wr[32], wz[32], wn[32];
  {
    const float* Wr = Whh + (size_t)e * HIDDEN + k0;
    const float* Wz = Whh + (size_t)(e + 512) * HIDDEN + k0;
    const float* Wn = Whh + (size_t)(e + 1024) * HIDDEN + k0;
#pragma unroll
    for (int i = 0; i < 32; i += 4) {
      *(float4*)&wr[i] = *(const float4*)(Wr + i);
      *(float4*)&wz[i] = *(const float4*)(Wz + i);
      *(float4*)&wn[i] = *(const float4*)(Wn + i);
    }
  }
  float br = bhh[e], bz = bhh[e + 512], bn = bhh[e + 1024];
  float hold = __uint_as_float(hpub[e] & ~511u);   // h^0[e], kept in-register thereafter
  for (int t = 0; t < TLEN; ++t) {
    // GI prefetch: independent of h, hides under the poll
    float gie = 0.f, giz = 0.f, gin = 0.f;
    if (p == 0) {
      const float* git = GI + (size_t)t * GATE3;
      gie = git[e]; giz = git[e + 512]; gin = git[e + 1024];
    }
    const u32* buf = hpub + (size_t)(t & 1) * HIDDEN + k0;
    u32 wt = (u32)t & 511u;
    u32x4 c[8];
    for (;;) {
      poll8(buf, c);
      u32 bad = 0;
#pragma unroll
      for (int i = 0; i < 8; ++i)
        bad |= (c[i][0] ^ wt) | (c[i][1] ^ wt) | (c[i][2] ^ wt) | (c[i][3] ^ wt);
      if (!(bad & 511u)) break;
    }
    float pr = 0.f, pz = 0.f, pn = 0.f;
#pragma unroll
    for (int i = 0; i < 8; ++i) {
#pragma unroll
      for (int j = 0; j < 4; ++j) {
        float h = __uint_as_float(c[i][j] & ~511u);
        pr += wr[i * 4 + j] * h;
        pz += wz[i * 4 + j] * h;
        pn += wn[i * 4 + j] * h;
      }
    }
#pragma unroll
    for (int m = 1; m < 16; m <<= 1) {
      pr += __shfl_xor(pr, m, 64);
      pz += __shfl_xor(pz, m, 64);
      pn += __shfl_xor(pn, m, 64);
    }
    if (p == 0) {
      float r = sigm(gie + pr + br);
      float z = sigm(giz + pz + bz);
      float n = tanhf(gin + r * (pn + bn));
      float hnew = (1.f - z) * n + z * hold;
      hold = hnew;
      HB[(size_t)t * HIDDEN + e] = f2bf(hnew);
      if (t + 1 < TLEN) {
        u32 pk = (__float_as_uint(hnew) & ~511u) | ((u32)(t + 1) & 511u);
        __hip_atomic_store(hpub + (size_t)((t + 1) & 1) * HIDDEN + e, pk,
                           __ATOMIC_RELAXED, __HIP_MEMORY_SCOPE_AGENT);
      }
    }
  }
}

// ---------- logits = HB @ WB^T + bout  (bf16 MFMA) ----------
__global__ __launch_bounds__(256) void kgemm(const unsigned short* HB,
                                             const unsigned short* WB,
                                             const float* bout, float* out) {
  __shared__ unsigned short As[64 * 264]; // 64 rows x (256+8 pad) bf16, per K-half
  int tid = threadIdx.x;
  int lane = tid & 63, w = tid >> 6;
  int j0 = blockIdx.x * 64;
  int t0 = blockIdx.y * 64;
  int jl = lane & 15, kq = lane >> 4;
  int j = j0 + w * 16 + jl;
  f32x4 acc[4];
#pragma unroll
  for (int i = 0; i < 4; ++i) acc[i] = (f32x4)(0.f);
  for (int kh = 0; kh < 2; ++kh) {
    __syncthreads();
#pragma unroll
    for (int i = 0; i < 8; ++i) {
      int c = tid + 256 * i;
      int row = c >> 5, off = (c & 31) * 8;
      u32x4 v = *(const u32x4*)(HB + (size_t)(t0 + row) * HIDDEN + kh * 256 + off);
      *(u32x4*)(As + row * 264 + off) = v;
    }
    __syncthreads();
    const unsigned short* Bp = WB + (size_t)j * HIDDEN + kh * 256 + kq * 8;
#pragma unroll
    for (int ks = 0; ks < 8; ++ks) {
      u32x4 bfrag = *(const u32x4*)(Bp + ks * 32);
#pragma unroll
      for (int tq = 0; tq < 4; ++tq) {
        u32x4 afrag = *(const u32x4*)(As + (tq * 16 + jl) * 264 + ks * 32 + kq * 8);
        asm volatile("v_mfma_f32_16x16x32_bf16 %0, %1, %2, %0"
                     : "+v"(acc[tq])
                     : "v"(afrag), "v"(bfrag));
      }
    }
  }
  asm volatile("s_nop 7\n\ts_nop 7\n\ts_nop 7" ::);
  bool jok = j < VTGT;
  float bj = jok ? bout[j] : 0.f;
#pragma unroll
  for (int tq = 0; tq < 4; ++tq) {
#pragma unroll
    for (int r = 0; r < 4; ++r) {
      int t = t0 + tq * 16 + kq * 4 + r;   // D: row=(lane>>4)*4+reg, col=lane&15
      if (jok) out[(size_t)t * VTGT + j] = acc[tq][r] + bj;
    }
  }
}

// ---------- fused logsumexp + subtract (row stays L2-resident between passes) ----------
__global__ __launch_bounds__(1024) void klsub(float* out) {
  int t = blockIdx.x, tid = threadIdx.x;
  float* row = out + (size_t)t * VTGT;
  float m = -INFINITY, s = 0.f;
  for (int jj = tid; jj < VTGT; jj += 1024) {
    float x = row[jj];
    if (x > m) { s = s * __expf(m - x) + 1.f; m = x; }
    else s += __expf(x - m);
  }
#pragma unroll
  for (int d = 1; d < 64; d <<= 1) {
    float mo = __shfl_xor(m, d, 64), so = __shfl_xor(s, d, 64);
    float mn = fmaxf(m, mo);
    s = s * __expf(m - mn) + so * __expf(mo - mn);
    m = mn;
  }
  __shared__ float sm[16], sv[16], sl;
  if ((tid & 63) == 0) { sm[tid >> 6] = m; sv[tid >> 6] = s; }
  __syncthreads();
  if (tid == 0) {
    for (int q = 1; q < 16; ++q) {
      float mo = sm[q], so = sv[q];
      float mn = fmaxf(m, mo);
      s = s * __expf(m - mn) + so * __expf(mo - mn);
      m = mn;
    }
    sl = m + logf(s);
  }
  __syncthreads();
  float l = sl;
  for (int jj = tid; jj < VTGT; jj += 1024) row[jj] -= l;
}

extern "C" void kernel_launch(void* const* d_in, const int* in_sizes, int n_in,
                              void* d_out, int out_size, void* d_ws, size_t ws_size,
                              hipStream_t stream) {
  const int*   source = (const int*)d_in[0];
  const int*   target = (const int*)d_in[1];
  const float* emb_e  = (const float*)d_in[2];
  const float* Wih_e  = (const float*)d_in[3];
  // d_in[4] = Whh_e: unused (h0 == 0)
  const float* bih_e  = (const float*)d_in[5];
  const float* bhh_e  = (const float*)d_in[6];
  const float* emb_d  = (const float*)d_in[7];
  const float* Wih_d  = (const float*)d_in[8];
  const float* Whh_d  = (const float*)d_in[9];
  const float* bih_d  = (const float*)d_in[10];
  const float* bhh_d  = (const float*)d_in[11];
  const float* Wout   = (const float*)d_in[12];
  const float* bout   = (const float*)d_in[13];
  float* out = (float*)d_out;
  char* ws = (char*)d_ws;

  // ws layout (bytes), all offsets 256-aligned
  float*          GI   = (float*)(ws + 0);                  // 3,145,728
  u32*            hpub = (u32*)(ws + 3145728);              // 4,096 (2 x 512 x 4B)
  float*          genc = (float*)(ws + 3149824);            //     6,144
  unsigned short* WB   = (unsigned short*)(ws + 3155968);   // 51,511,296
  unsigned short* HB   = (unsigned short*)(ws + 54667264);  //   524,288
  // total ws use ~55.2 MB

  kenc1<<<6, 256, 0, stream>>>(source, emb_e, Wih_e, bih_e, genc);
  kenc2<<<1, 512, 0, stream>>>(genc, bhh_e, hpub);
  kgi<<<dim3(12, 16), 256, 0, stream>>>(target, emb_d, Wih_d, bih_d, GI);
  kwout<<<4096, 256, 0, stream>>>(Wout, WB);
  krec<<<RKB, 64, 0, stream>>>(Whh_d, bhh_d, GI, hpub, HB);
  kgemm<<<dim3((VTGT + 63) / 64, 8), 256, 0, stream>>>(HB, WB, bout, out);
  klsub<<<512, 1024, 0, stream>>>(out);
}

// Round 4
// 943.089 us; speedup vs baseline: 1.6243x; 1.6243x over previous
//
#include <hip/hip_runtime.h>
#include <stdint.h>

#define HIDDEN 512
#define EMBED  256
#define VTGT   50257
#define TLEN   512
#define GATE3  1536
#define REC_B  16
#define GEMM_B 224
#define NBLK   (REC_B + GEMM_B)
#define NJT    ((VTGT + 127) / 128)   // 393 j-tiles of 128

typedef float f32x4 __attribute__((ext_vector_type(4)));
typedef unsigned int u32;
typedef unsigned int u32x4 __attribute__((ext_vector_type(4)));

__device__ __forceinline__ unsigned short f2bf(float f) {
  union { float f; unsigned u; } v; v.f = f;
  unsigned u = v.u;
  unsigned r = (u + 0x7FFFu + ((u >> 16) & 1u)) >> 16;
  return (unsigned short)r;
}

__device__ __forceinline__ float sigm(float x) {
  return 1.f / (1.f + __expf(-x));
}

// single coherent dword poll (one RTT per sample)
__device__ __forceinline__ u32 cpoll(const u32* p) {
  u32 v;
  asm volatile("global_load_dword %0, %1, off sc0 sc1\n\ts_waitcnt vmcnt(0)"
               : "=v"(v) : "v"(p) : "memory");
  return v;
}
// 4x dwordx4 coherent, single flight
__device__ __forceinline__ void cload4x4(const u32* p, u32x4& a, u32x4& b,
                                         u32x4& c, u32x4& d) {
  asm volatile(
      "global_load_dwordx4 %0, %4, off sc0 sc1\n\t"
      "global_load_dwordx4 %1, %4, off offset:16 sc0 sc1\n\t"
      "global_load_dwordx4 %2, %4, off offset:32 sc0 sc1\n\t"
      "global_load_dwordx4 %3, %4, off offset:48 sc0 sc1\n\t"
      "s_waitcnt vmcnt(0)"
      : "=v"(a), "=v"(b), "=v"(c), "=v"(d) : "v"(p) : "memory");
}
__device__ __forceinline__ void cstore(u32* p, u32 v) {
  asm volatile("global_store_dword %0, %1, off sc0 sc1" :: "v"(p), "v"(v) : "memory");
}

// ---------- encoder: gi = Wih_e @ x_last + bih_e ----------
__global__ void kenc1(const int* source, const float* emb_e, const float* Wih_e,
                      const float* bih_e, float* genc) {
  __shared__ float xs[EMBED];
  int tid = threadIdx.x;
  int tok = source[511];
  if (tid < EMBED) xs[tid] = emb_e[(size_t)tok * EMBED + tid];
  __syncthreads();
  int j = blockIdx.x * 256 + tid;
  const float* w = Wih_e + (size_t)j * EMBED;
  float acc = bih_e[j];
  for (int k = 0; k < EMBED; k += 4) {
    float4 wv = *(const float4*)(w + k);
    acc += wv.x * xs[k] + wv.y * xs[k + 1] + wv.z * xs[k + 2] + wv.w * xs[k + 3];
  }
  genc[j] = acc;
}

// ---------- encoder gates: write tagged h_0 into hs slot 0 ----------
__global__ void kenc2(const float* genc, const float* bhh_e, u32* hs) {
  int e = threadIdx.x; // 512 threads
  float r = sigm(genc[e] + bhh_e[e]);
  float z = sigm(genc[e + 512] + bhh_e[e + 512]);
  float n = tanhf(genc[e + 1024] + r * bhh_e[e + 1024]);
  float h = (1.f - z) * n;
  hs[e] = (__float_as_uint(h) & ~511u) | 256u;  // tag(0) = 256
}

// ---------- GI[t][j] = Wih_d @ relu(emb_d[tok_t]) + bih_d ----------
__global__ __launch_bounds__(256) void kgi(const int* target, const float* emb_d,
                                           const float* Wih_d, const float* bih_d,
                                           float* GI) {
  __shared__ float Xs[32][EMBED];
  int tid = threadIdx.x;
  int j0 = blockIdx.x * 128;
  int t0 = blockIdx.y * 32;
  for (int idx = tid; idx < 32 * EMBED; idx += 256) {
    int tt = idx >> 8, c = idx & 255;
    int t = t0 + tt;
    int tok = (t == 0) ? 0 : target[t - 1];
    float v = emb_d[(size_t)tok * EMBED + c];
    Xs[tt][c] = v > 0.f ? v : 0.f;
  }
  __syncthreads();
  int jl = tid & 127, tg = tid >> 7;
  int j = j0 + jl;
  const float* w = Wih_d + (size_t)j * EMBED;
  float acc[16];
#pragma unroll
  for (int i = 0; i < 16; ++i) acc[i] = 0.f;
  for (int k = 0; k < EMBED; k += 4) {
    float4 wv = *(const float4*)(w + k);
#pragma unroll
    for (int i = 0; i < 16; ++i) {
      int tl = tg * 16 + i;
      acc[i] += wv.x * Xs[tl][k] + wv.y * Xs[tl][k + 1] +
                wv.z * Xs[tl][k + 2] + wv.w * Xs[tl][k + 3];
    }
  }
  float b = bih_d[j];
#pragma unroll
  for (int i = 0; i < 16; ++i) {
    int t = t0 + tg * 16 + i;
    GI[(size_t)t * GATE3 + j] = acc[i] + b;
  }
}

// ---------- recurrence path: 16 blocks x 512 thr, 1-dword poll + LDS bcast ----------
__device__ void rec_path(int bid, const float* Whh, const float* bhh,
                         const float* GI, u32* hs, u32* stepv, char* SM) {
  int tid = threadIdx.x;
  int r = tid >> 4, p = tid & 15;     // row 0..31, k-slice 0..15
  int e = bid * 32 + r;
  int k0 = p * 32;
  float* hbuf = (float*)SM;           // [2][576] padded stride 36/32
  float wr[32], wz[32], wn[32];
  {
    const float* Wr = Whh + (size_t)e * HIDDEN + k0;
    const float* Wz = Whh + (size_t)(e + 512) * HIDDEN + k0;
    const float* Wn = Whh + (size_t)(e + 1024) * HIDDEN + k0;
#pragma unroll
    for (int i = 0; i < 32; i += 4) {
      *(float4*)&wr[i] = *(const float4*)(Wr + i);
      *(float4*)&wz[i] = *(const float4*)(Wz + i);
      *(float4*)&wn[i] = *(const float4*)(Wn + i);
    }
  }
  float br = bhh[e], bz = bhh[e + 512], bn = bhh[e + 1024];
  __builtin_amdgcn_s_setprio(1);
  int wslot = (tid >> 5) * 36 + (tid & 31);
  int eslot = (e >> 5) * 36 + (e & 31);
  for (int t = 0; t < TLEN; ++t) {
    int par = t & 1;
    float gie = 0.f, giz = 0.f, gin = 0.f;
    if (p == 0) {
      const float* git = GI + (size_t)t * GATE3;
      gie = git[e]; giz = git[e + 512]; gin = git[e + 1024];
    }
    u32 want = 256u + ((u32)t & 255u);
    const u32* src = hs + (size_t)t * HIDDEN + tid;
    u32 v;
    do { v = cpoll(src); } while ((v & 511u) != want);
    hbuf[par * 576 + wslot] = __uint_as_float(v & ~511u);
    __syncthreads();
    if (bid == 0 && tid == 0) cstore(stepv, (u32)t);  // slot t globally ready
    const float* hp = hbuf + par * 576 + p * 36;
    float pr = 0.f, pz = 0.f, pn = 0.f;
#pragma unroll
    for (int i = 0; i < 32; i += 4) {
      float4 hv = *(const float4*)(hp + i);
      pr += wr[i] * hv.x + wr[i + 1] * hv.y + wr[i + 2] * hv.z + wr[i + 3] * hv.w;
      pz += wz[i] * hv.x + wz[i + 1] * hv.y + wz[i + 2] * hv.z + wz[i + 3] * hv.w;
      pn += wn[i] * hv.x + wn[i + 1] * hv.y + wn[i + 2] * hv.z + wn[i + 3] * hv.w;
    }
#pragma unroll
    for (int m = 1; m < 16; m <<= 1) {
      pr += __shfl_xor(pr, m);
      pz += __shfl_xor(pz, m);
      pn += __shfl_xor(pn, m);
    }
    if (p == 0) {
      float rg = sigm(gie + pr + br);
      float z  = sigm(giz + pz + bz);
      float n  = tanhf(gin + rg * (pn + bn));
      float hold = hbuf[par * 576 + eslot];
      float hnew = (1.f - z) * n + z * hold;
      u32 pk = (__float_as_uint(hnew) & ~511u) | (256u + ((u32)(t + 1) & 255u));
      cstore(hs + (size_t)(t + 1) * HIDDEN + e, pk);
    }
    // no tail barrier: next step writes the other hbuf parity
  }
  if (bid == 0) {  // confirm final slot 512, release stepv=512 for last GEMM tile
    u32 want = 256u;  // tag(512) = 256 + (512 & 255)
    const u32* src = hs + (size_t)TLEN * HIDDEN + tid;
    u32 v;
    do { v = cpoll(src); } while ((v & 511u) != want);
    __syncthreads();
    if (tid == 0) cstore(stepv, (u32)TLEN);
  }
}

// ---------- GEMM path: persistent blocks, tag-verified A, on-the-fly bf16 B ----------
__device__ void gemm_path(int g, const u32* hs, u32* stepv, const float* Wout,
                          const float* bout, float* out, char* SM) {
  unsigned short* As = (unsigned short*)SM;   // [64][520] bf16
  int tid = threadIdx.x;
  int w = tid >> 6, lane = tid & 63;
  int jl = lane & 15, kq = lane >> 4;
  int srow = tid >> 3, scg = tid & 7;          // stage: row 0..63, 64-word col group
  for (int t0i = 0; t0i < 8; ++t0i) {
    int t0 = t0i * 64;
    if (tid == 0) {
      while ((int)cpoll(stepv) < t0 + 64) {}
    }
    __syncthreads();
    // stage A tile: rows t0..t0+63 from tagged hs slots t0+1..t0+64
    int slot = t0 + srow + 1;
    u32 want = 256u + ((u32)slot & 255u);
    const u32* sbase = hs + (size_t)slot * HIDDEN + scg * 64;
#pragma unroll
    for (int b = 0; b < 4; ++b) {
      const u32* sp = sbase + b * 16;
      u32x4 c0, c1, c2, c3;
      for (;;) {
        cload4x4(sp, c0, c1, c2, c3);
        u32 bad = 0;
#pragma unroll
        for (int q = 0; q < 4; ++q)
          bad |= (c0[q] ^ want) | (c1[q] ^ want) | (c2[q] ^ want) | (c3[q] ^ want);
        if (!(bad & 511u)) break;
      }
      u32 dw[8];
#pragma unroll
      for (int q = 0; q < 4; ++q) {
        u32x4 cq = (q == 0) ? c0 : (q == 1) ? c1 : (q == 2) ? c2 : c3;
        float f0 = __uint_as_float(cq[0] & ~511u);
        float f1 = __uint_as_float(cq[1] & ~511u);
        float f2 = __uint_as_float(cq[2] & ~511u);
        float f3 = __uint_as_float(cq[3] & ~511u);
        dw[q * 2]     = (u32)f2bf(f0) | ((u32)f2bf(f1) << 16);
        dw[q * 2 + 1] = (u32)f2bf(f2) | ((u32)f2bf(f3) << 16);
      }
      *(u32x4*)&As[srow * 520 + scg * 64 + b * 16]     = *(u32x4*)&dw[0];
      *(u32x4*)&As[srow * 520 + scg * 64 + b * 16 + 8] = *(u32x4*)&dw[4];
    }
    __syncthreads();
    for (int jt = g; jt < NJT; jt += GEMM_B) {
      int j = jt * 128 + w * 16 + jl;
      int jc = j < VTGT ? j : VTGT - 1;
      const float* Bp = Wout + (size_t)jc * HIDDEN + kq * 8;
      f32x4 acc[4];
#pragma unroll
      for (int i = 0; i < 4; ++i) acc[i] = (f32x4)(0.f);
#pragma unroll
      for (int ks = 0; ks < 16; ++ks) {
        float4 b0 = *(const float4*)(Bp + ks * 32);
        float4 b1 = *(const float4*)(Bp + ks * 32 + 4);
        u32x4 bf;
        bf[0] = (u32)f2bf(b0.x) | ((u32)f2bf(b0.y) << 16);
        bf[1] = (u32)f2bf(b0.z) | ((u32)f2bf(b0.w) << 16);
        bf[2] = (u32)f2bf(b1.x) | ((u32)f2bf(b1.y) << 16);
        bf[3] = (u32)f2bf(b1.z) | ((u32)f2bf(b1.w) << 16);
#pragma unroll
        for (int tq = 0; tq < 4; ++tq) {
          u32x4 af = *(const u32x4*)&As[(tq * 16 + jl) * 520 + ks * 32 + kq * 8];
          asm volatile("v_mfma_f32_16x16x32_bf16 %0, %1, %2, %0"
                       : "+v"(acc[tq]) : "v"(af), "v"(bf));
        }
      }
      asm volatile("s_nop 7\n\ts_nop 7\n\ts_nop 7" ::);
      bool jok = j < VTGT;
      float bj = jok ? bout[j] : 0.f;
#pragma unroll
      for (int tq = 0; tq < 4; ++tq)
#pragma unroll
        for (int rr = 0; rr < 4; ++rr) {
          int t = t0 + tq * 16 + kq * 4 + rr;  // D: row=(lane>>4)*4+reg, col=lane&15
          if (jok) out[(size_t)t * VTGT + j] = acc[tq][rr] + bj;
        }
    }
    __syncthreads();  // all As reads done before next t0 restages
  }
}

// ---------- fused mega-kernel: 16 rec blocks + 224 persistent GEMM blocks ----------
__global__ __launch_bounds__(512) void kmain(const float* Whh, const float* bhh,
                                             const float* GI, u32* hs, u32* stepv,
                                             const float* Wout, const float* bout,
                                             float* out) {
  __shared__ __align__(16) char SM[64 * 520 * 2];  // 66.5 KB union
  int bid = blockIdx.x;
  if (bid < REC_B) rec_path(bid, Whh, bhh, GI, hs, stepv, SM);
  else gemm_path(bid - REC_B, hs, stepv, Wout, bout, out, SM);
}

// ---------- fused logsumexp + subtract ----------
__global__ __launch_bounds__(1024) void klsub(float* out) {
  int t = blockIdx.x, tid = threadIdx.x;
  float* row = out + (size_t)t * VTGT;
  float m = -INFINITY, s = 0.f;
  for (int jj = tid; jj < VTGT; jj += 1024) {
    float x = row[jj];
    if (x > m) { s = s * __expf(m - x) + 1.f; m = x; }
    else s += __expf(x - m);
  }
#pragma unroll
  for (int d = 1; d < 64; d <<= 1) {
    float mo = __shfl_xor(m, d, 64), so = __shfl_xor(s, d, 64);
    float mn = fmaxf(m, mo);
    s = s * __expf(m - mn) + so * __expf(mo - mn);
    m = mn;
  }
  __shared__ float sm[16], sv[16], sl;
  if ((tid & 63) == 0) { sm[tid >> 6] = m; sv[tid >> 6] = s; }
  __syncthreads();
  if (tid == 0) {
    for (int q = 1; q < 16; ++q) {
      float mo = sm[q], so = sv[q];
      float mn = fmaxf(m, mo);
      s = s * __expf(m - mn) + so * __expf(mo - mn);
      m = mn;
    }
    sl = m + logf(s);
  }
  __syncthreads();
  float l = sl;
  for (int jj = tid; jj < VTGT; jj += 1024) row[jj] -= l;
}

extern "C" void kernel_launch(void* const* d_in, const int* in_sizes, int n_in,
                              void* d_out, int out_size, void* d_ws, size_t ws_size,
                              hipStream_t stream) {
  const int*   source = (const int*)d_in[0];
  const int*   target = (const int*)d_in[1];
  const float* emb_e  = (const float*)d_in[2];
  const float* Wih_e  = (const float*)d_in[3];
  // d_in[4] = Whh_e: unused (h0 == 0)
  const float* bih_e  = (const float*)d_in[5];
  const float* bhh_e  = (const float*)d_in[6];
  const float* emb_d  = (const float*)d_in[7];
  const float* Wih_d  = (const float*)d_in[8];
  const float* Whh_d  = (const float*)d_in[9];
  const float* bih_d  = (const float*)d_in[10];
  const float* bhh_d  = (const float*)d_in[11];
  const float* Wout   = (const float*)d_in[12];
  const float* bout   = (const float*)d_in[13];
  float* out = (float*)d_out;
  char* ws = (char*)d_ws;

  // ws layout (bytes)
  float* GI    = (float*)(ws + 0);          // 3,145,728
  u32*   hs    = (u32*)(ws + 3145728);      // 1,050,624 (513 x 512 tagged f32)
  u32*   stepv = (u32*)(ws + 4196352);      //       256
  float* genc  = (float*)(ws + 4196608);    //     6,144
  // total ws use ~4.2 MB

  hipMemsetAsync(hs, 0, 1050624 + 256, stream);  // invalidate tags + stepv each call
  kenc1<<<6, 256, 0, stream>>>(source, emb_e, Wih_e, bih_e, genc);
  kenc2<<<1, 512, 0, stream>>>(genc, bhh_e, hs);
  kgi<<<dim3(12, 16), 256, 0, stream>>>(target, emb_d, Wih_d, bih_d, GI);
  kmain<<<NBLK, 512, 0, stream>>>(Whh_d, bhh_d, GI, hs, stepv, Wout, bout, out);
  klsub<<<512, 1024, 0, stream>>>(out);
}